// Round 7
// baseline (436.491 us; speedup 1.0000x reference)
//
#include <hip/hip_runtime.h>
#include <hip/hip_fp16.h>

#define D 1024
#define LOG2D 10
#define S_LEN 4096
#define BATCH 4
#define NROWS (BATCH * S_LEN) /* 16384 */
#define PI_F 3.14159265358979323846f

typedef _Float16 f16x8 __attribute__((ext_vector_type(8)));
typedef float f32x4 __attribute__((ext_vector_type(4)));

__device__ __forceinline__ float2 cmul(float2 a, float2 b) {
    return make_float2(a.x * b.x - a.y * b.y, a.x * b.y + a.y * b.x);
}

__device__ __forceinline__ float fast_tanh(float v) {
    float e = __expf(2.0f * v);
    return 1.0f - 2.0f * __builtin_amdgcn_rcpf(e + 1.0f);
}

__device__ __forceinline__ void g2lds16(const void* g, void* l) {
    __builtin_amdgcn_global_load_lds(
        (const __attribute__((address_space(1))) unsigned int*)g,
        (__attribute__((address_space(3))) unsigned int*)l, 16, 0, 0);
}

// ---------------- fp32 -> fp16 conversion (x and the 4 weight matrices) ----
__global__ __launch_bounds__(256) void convert_all(
    const float* __restrict__ x,
    const float* __restrict__ w0, const float* __restrict__ w1,
    const float* __restrict__ w2, const float* __restrict__ w3,
    __half* __restrict__ xh,
    __half* __restrict__ h0, __half* __restrict__ h1,
    __half* __restrict__ h2, __half* __restrict__ h3)
{
    const int b = blockIdx.x;
    const float* s;
    __half* d;
    int li;
    if (b < 16384) { s = x; d = xh; li = b; }
    else {
        int t = b - 16384;
        int r = t >> 10;
        li = t & 1023;
        s = (r == 0) ? w0 : (r == 1) ? w1 : (r == 2) ? w2 : w3;
        d = (r == 0) ? h0 : (r == 1) ? h1 : (r == 2) ? h2 : h3;
    }
    const int idx = li * 256 + threadIdx.x;  // float4 index
    float4 v = ((const float4*)s)[idx];
    __half2 lo = __floats2half2_rn(v.x, v.y);
    __half2 hi = __floats2half2_rn(v.z, v.w);
    ((__half2*)d)[2 * idx + 0] = lo;
    ((__half2*)d)[2 * idx + 1] = hi;
}

// ------- Fused dual MFMA GEMM (round-1 proven structure, 89-91 us) --------
// O = {tanh(Xh*W0^T+b0), tanh(Xh*W1^T+b1)} stored INTERLEAVED as __half2.
// 128x128 tile, BK=64 (16 k-tiles, 64 MFMA per barrier pair), 256 thr.
// LDS [row][64] halves, 8 chunks of 16B per row, chunk q stored at slot
// q ^ (row&7) -> global_load_lds stays lane-contiguous, ds_read_b128 2-way max.
// XCD-swizzled block mapping for L2 locality.
__global__ __launch_bounds__(256, 2) void gemm_mfma2(
    const __half* __restrict__ Xh,
    const __half* __restrict__ W0, const float* __restrict__ b0,
    const __half* __restrict__ W1, const float* __restrict__ b1,
    __half2* __restrict__ KV)
{
    const int idx = blockIdx.x;
    const int xcd = idx & 7;
    const int j = idx >> 3;           // 0..127
    const int n0 = (j & 7) * 128;
    const int m0 = (xcd * 16 + (j >> 3)) * 128;

    __shared__ __align__(16) __half As[128 * 64];
    __shared__ __align__(16) __half B0s[128 * 64];
    __shared__ __align__(16) __half B1s[128 * 64];

    const int tid = threadIdx.x;
    const int wave = tid >> 6;
    const int lane = tid & 63;

    // staging: one g2lds = 64 lanes x 16B = 8 rows x 8 chunks.
    const int srow = lane >> 3;
    const int schunk = (lane & 7) ^ (lane >> 3);

    const __half* gA[4];
    const __half* gB0[4];
    const __half* gB1[4];
    int loff[4];
#pragma unroll
    for (int c = 0; c < 4; ++c) {
        const int rbase = wave * 32 + c * 8;         // multiple of 8
        gA[c]  = Xh + (size_t)(m0 + rbase + srow) * 1024 + schunk * 8;
        gB0[c] = W0 + (size_t)(n0 + rbase + srow) * 1024 + schunk * 8;
        gB1[c] = W1 + (size_t)(n0 + rbase + srow) * 1024 + schunk * 8;
        loff[c] = rbase * 64;                         // half units
    }

    const int wm = (wave & 1) * 64;
    const int wn = (wave >> 1) * 64;
    const int quad = lane >> 4;
    const int l15 = lane & 15;

    // frag read offsets: row R, k-slice kk (0/1): chunk c=(kk<<2)|quad at
    // slot c ^ (R&7); R&7 = l15&7 here (wm, i*16 are multiples of 8).
    int aoff[2][4], boff[2][4];
#pragma unroll
    for (int kk = 0; kk < 2; ++kk)
#pragma unroll
        for (int i = 0; i < 4; ++i) {
            const int Ra = wm + i * 16 + l15;
            aoff[kk][i] = Ra * 64 + ((((kk << 2) | quad)) ^ (l15 & 7)) * 8;
            const int Rb = wn + i * 16 + l15;
            boff[kk][i] = Rb * 64 + ((((kk << 2) | quad)) ^ (l15 & 7)) * 8;
        }

    f32x4 acc0[4][4], acc1[4][4];
#pragma unroll
    for (int i = 0; i < 4; ++i)
#pragma unroll
        for (int jj = 0; jj < 4; ++jj) {
            acc0[i][jj] = (f32x4){0.f, 0.f, 0.f, 0.f};
            acc1[i][jj] = (f32x4){0.f, 0.f, 0.f, 0.f};
        }

    for (int kt = 0; kt < 16; ++kt) {
        const int kh = kt * 64;
        __syncthreads();
#pragma unroll
        for (int c = 0; c < 4; ++c) {
            g2lds16(gA[c] + kh,  As  + loff[c]);
            g2lds16(gB0[c] + kh, B0s + loff[c]);
            g2lds16(gB1[c] + kh, B1s + loff[c]);
        }
        __syncthreads();

#pragma unroll
        for (int kk = 0; kk < 2; ++kk) {
            f16x8 af[4], bf0[4], bf1[4];
#pragma unroll
            for (int i = 0; i < 4; ++i) af[i] = *(const f16x8*)(As + aoff[kk][i]);
#pragma unroll
            for (int jj = 0; jj < 4; ++jj) {
                bf0[jj] = *(const f16x8*)(B0s + boff[kk][jj]);
                bf1[jj] = *(const f16x8*)(B1s + boff[kk][jj]);
            }
#pragma unroll
            for (int i = 0; i < 4; ++i)
#pragma unroll
                for (int jj = 0; jj < 4; ++jj) {
                    acc0[i][jj] = __builtin_amdgcn_mfma_f32_16x16x32_f16(af[i], bf0[jj], acc0[i][jj], 0, 0, 0);
                    acc1[i][jj] = __builtin_amdgcn_mfma_f32_16x16x32_f16(af[i], bf1[jj], acc1[i][jj], 0, 0, 0);
                }
        }
    }

    // epilogue: C/D frag mapping col=lane&15, row=quad*4+reg; interleaved pair
#pragma unroll
    for (int jj = 0; jj < 4; ++jj) {
        const int n = n0 + wn + jj * 16 + l15;
        const float bv0 = b0[n];
        const float bv1 = b1[n];
#pragma unroll
        for (int i = 0; i < 4; ++i) {
            const int mbase = m0 + wm + i * 16 + quad * 4;
#pragma unroll
            for (int r = 0; r < 4; ++r) {
                const __half h0 = __float2half(fast_tanh(acc0[i][jj][r] + bv0));
                const __half h1 = __float2half(fast_tanh(acc1[i][jj][r] + bv1));
                KV[(size_t)(mbase + r) * 1024 + n] = __halves2half2(h0, h1);
            }
        }
    }
}

// ================= register FFT-32 building blocks (proven) ================
__device__ constexpr int br5(int i) {
    return ((i & 1) << 4) | ((i & 2) << 2) | (i & 4) | ((i & 8) >> 2) | ((i & 16) >> 4);
}

// W32^k twiddles as compile-time constants (k static after unroll).
// INV=0: e^{-2pi i k/32}; INV=1: conjugate.
template<int INV>
__device__ __forceinline__ float2 w32c(int k) {
    constexpr float C[16] = {
        1.0f, 0.98078528f, 0.92387953f, 0.83146961f,
        0.70710678f, 0.55557023f, 0.38268343f, 0.19509032f,
        0.0f, -0.19509032f, -0.38268343f, -0.55557023f,
        -0.70710678f, -0.83146961f, -0.92387953f, -0.98078528f};
    constexpr float Sn[16] = {
        0.0f, 0.19509032f, 0.38268343f, 0.55557023f,
        0.70710678f, 0.83146961f, 0.92387953f, 0.98078528f,
        1.0f, 0.98078528f, 0.92387953f, 0.83146961f,
        0.70710678f, 0.55557023f, 0.38268343f, 0.19509032f};
    return make_float2(C[k], INV ? Sn[k] : -Sn[k]);
}

// In-register 32-point FFT. Input in registers bit-reversed, output natural.
template<int INV>
__device__ __forceinline__ void fft32(float2* z) {
#pragma unroll
    for (int s = 0; s < 5; ++s) {
#pragma unroll
        for (int j = 0; j < 16; ++j) {
            const int half = 1 << s;
            const int blk = j >> s;
            const int off = j & (half - 1);
            const int i0 = (blk << (s + 1)) + off;
            const int i1 = i0 + half;
            const float2 w = w32c<INV>(off << (4 - s));
            const float2 v = cmul(z[i1], w);
            z[i1] = make_float2(z[i0].x - v.x, z[i0].y - v.y);
            z[i0] = make_float2(z[i0].x + v.x, z[i0].y + v.y);
        }
    }
}

// ================= register-FFT bind kernel (forward only) =================
// Algebraic simplification: for z = k + iv,  P = Fk*Fv = W(j) + conj(W(-j))
// with W = -i/4 * Z^2 (LANE-LOCAL: no Hermitian unpack, no mirror LDS round).
// Symmetrization commutes with the row-sum, so bind accumulates S = sum(W)
// only; retrieve computes Ff = S[j] + conj(S[-j]) on the fly.
// OCCUPANCY PIN (round-6 fix): the default allocator heuristic targeted
// 4 waves/EU (128 VGPR) and spilled ~40 regs/row (~100MB scratch traffic,
// FETCH 104MB / WRITE 70MB vs 64/8 legitimate). waves_per_eu(2,2) closes
// the range -> 256-VGPR budget, no spill; LDS (16.9KB/block) caps us at
// ~2.25 waves/SIMD anyway, so nothing is lost.
#define BROWS 4
__global__ __attribute__((amdgpu_flat_work_group_size(64, 64),
                          amdgpu_waves_per_eu(2, 2)))
void bind_accum_kernel(
    const unsigned int* __restrict__ KV, float2* __restrict__ Fs)
{
    __shared__ float2 T[2][33 * 32];
    const int tid = threadIdx.x;
    const int grp = tid >> 5;
    const int t = tid & 31;
    const int row0 = blockIdx.x * (2 * BROWS) + grp * BROWS;
    const int b = row0 >> 12;   // 8-row chunks never straddle batches
    float2* Tr = T[grp];

    float sn_, cs_;
    __sincosf((PI_F / 512.0f) * (float)t, &sn_, &cs_);
    const float2 w1 = make_float2(cs_, -sn_);

    float2 acc[32];
#pragma unroll
    for (int i = 0; i < 32; ++i) acc[i] = make_float2(0.f, 0.f);

    for (int r = 0; r < BROWS; ++r) {
        const unsigned int* src = KV + ((size_t)(row0 + r) << 10);
        float2 z[32];
#pragma unroll
        for (int n1 = 0; n1 < 32; ++n1) {
            const unsigned int u = src[(n1 << 5) + t];
            const __half2 hv = *(const __half2*)&u;   // {K, V}
            z[br5(n1)] = make_float2(__half2float(hv.x), __half2float(hv.y));
        }
        fft32<0>(z);                 // A[k1] over n1
        {
            float2 tw = make_float2(1.0f, 0.0f);
#pragma unroll
            for (int k1 = 0; k1 < 32; ++k1) { z[k1] = cmul(z[k1], tw); tw = cmul(tw, w1); }
        }
        // transpose: write [k1][t], read [t][n2] (cross-lane, same wave ->
        // DS pipe in-order; sched_barrier pins compiler ordering)
#pragma unroll
        for (int k1 = 0; k1 < 32; ++k1) Tr[33 * k1 + t] = z[k1];
        __builtin_amdgcn_sched_barrier(0);
#pragma unroll
        for (int n2 = 0; n2 < 32; ++n2) z[br5(n2)] = Tr[33 * t + n2];
        fft32<0>(z);                 // Z[j], j = t + 32*k2
        __builtin_amdgcn_sched_barrier(0);  // next r's Tr writes stay after reads
        // W = -i/4 * Z^2 = (x*y/2, (y^2 - x^2)/4), accumulate
#pragma unroll
        for (int k2 = 0; k2 < 32; ++k2) {
            const float zx = z[k2].x, zy = z[k2].y;
            acc[k2].x = __builtin_fmaf(zx * zy, 0.5f, acc[k2].x);
            acc[k2].y += 0.25f * (zy * zy - zx * zx);
        }
    }

    // pair-reduce the two half-wave groups (same j set, different rows)
    float2* FsB = Fs + ((size_t)b << 10);
#pragma unroll
    for (int k2 = 0; k2 < 32; ++k2) {
        const float sx = acc[k2].x + __shfl_xor(acc[k2].x, 32);
        const float sy = acc[k2].y + __shfl_xor(acc[k2].y, 32);
        if (grp == 0) {
            atomicAdd(&FsB[(k2 << 5) + t].x, sx);
            atomicAdd(&FsB[(k2 << 5) + t].y, sy);
        }
    }
}

// ===================== register-FFT retrieve kernel ========================
#define RETR_ROWS 4
__global__ __launch_bounds__(128) void retrieve_kernel(
    const unsigned int* __restrict__ QR,
    const float2* __restrict__ Fs, const float* __restrict__ x, float* __restrict__ out)
{
    // per-row transpose buffer, pad 33 (row stride 33 float2) -> conflict-free
    __shared__ __align__(16) float2 T[RETR_ROWS][33 * 32];
    const int tid = threadIdx.x;
    const int lr = tid >> 5;     // local row 0..3
    const int t  = tid & 31;     // lane within row = n2 / k1 / n1 role
    const int row = blockIdx.x * RETR_ROWS + lr;
    const int b = row >> 12;
    const size_t base = (size_t)row << 10;
    float2* Tr = T[lr];

    // ---- load z[n1] = Q + i*R at n = 32*n1 + t (interleaved u32) ---------
    float2 z[32];
    const unsigned int* src = QR + base;
#pragma unroll
    for (int n1 = 0; n1 < 32; ++n1) {
        const unsigned int u = src[(n1 << 5) + t];
        const __half2 hv = *(const __half2*)&u;   // {Q, R}
        z[br5(n1)] = make_float2(__half2float(hv.x), __half2float(hv.y));
    }
    fft32<0>(z);                     // A[k1] over n1 (natural order)

    // ---- middle twiddle W1024^{-t*k1}: sincos once + recurrence ----------
    float sn_, cs_;
    __sincosf((PI_F / 512.0f) * (float)t, &sn_, &cs_);
    {
        const float2 w1 = make_float2(cs_, -sn_);
        float2 tw = make_float2(1.0f, 0.0f);
#pragma unroll
        for (int k1 = 0; k1 < 32; ++k1) { z[k1] = cmul(z[k1], tw); tw = cmul(tw, w1); }
    }

    // ---- transpose #1: write [k1][t], read [t][n2] (bitrev into regs) ----
#pragma unroll
    for (int k1 = 0; k1 < 32; ++k1) Tr[33 * k1 + t] = z[k1];
    __syncthreads();
#pragma unroll
    for (int n2 = 0; n2 < 32; ++n2) z[br5(n2)] = Tr[33 * t + n2];
    fft32<0>(z);                     // z[k2] = Z[t + 32*k2]
    __syncthreads();                 // WAR: transpose reads done

    // ---- mirror round: Z -> LDS [k2][t]; read Z[1024-j] from mirror ------
#pragma unroll
    for (int k2 = 0; k2 < 32; ++k2) Tr[33 * k2 + t] = z[k2];
    __syncthreads();

    float2 h[32];
    const float2* FsB = Fs + ((size_t)b << 10);
    const int mc = (32 - t) & 31;
    const int me = (t == 0) ? 1 : 0;   // t=0 mirrors onto itself, shifted row
#pragma unroll
    for (int k2 = 0; k2 < 32; ++k2) {
        const int ma = (31 - k2 + me) & 31;
        float2 Zc = Tr[33 * ma + mc];
        Zc.y = -Zc.y;                  // conj(Z[1024-j])
        const float2 Zt = z[k2];       // Z[j], j = t + 32*k2
        const float2 Fq = make_float2(0.5f * (Zt.x + Zc.x), 0.5f * (Zt.y + Zc.y));
        const float2 Fr = make_float2(0.5f * (Zt.y - Zc.y), -0.5f * (Zt.x - Zc.x));
        const float2 g2 = make_float2(Fq.x - (Fr.x * Fr.x + Fr.y * Fr.y), -Fq.y);
        // Fs holds UNSYMMETRIZED S = sum(W); Ff = S[j] + conj(S[-j])
        const int jdx = (k2 << 5) + t;
        const float2 Sf = FsB[jdx];
        const float2 Sm = FsB[(1024 - jdx) & 1023];
        const float2 Ff = make_float2(Sf.x + Sm.x, Sf.y - Sm.y);
        h[br5(k2)] = cmul(Ff, g2);     // H[j], bitrev for inverse stage 1
    }

    // ---- inverse: same distribution (k = t mod 32) -> register-local -----
    fft32<1>(h);                     // over k1
    {
        const float2 w1c = make_float2(cs_, sn_);   // W1024^{+n1*t}
        float2 tw = make_float2(1.0f, 0.0f);
#pragma unroll
        for (int n1 = 0; n1 < 32; ++n1) { h[n1] = cmul(h[n1], tw); tw = cmul(tw, w1c); }
    }
    __syncthreads();                 // WAR: mirror reads done before overwrite
#pragma unroll
    for (int n1 = 0; n1 < 32; ++n1) Tr[33 * n1 + t] = h[n1];
    __syncthreads();
#pragma unroll
    for (int k2 = 0; k2 < 32; ++k2) h[br5(k2)] = Tr[33 * t + k2];
    fft32<1>(h);                     // h[n2] = y[t + 32*n2] (unscaled)

    // ---- out = x + real(y)/1024, coalesced (32 consecutive lanes) --------
    const float* xr = x + base;
    float* outr = out + base;
#pragma unroll
    for (int n2 = 0; n2 < 32; ++n2) {
        const int g = (n2 << 5) + t;
        outr[g] = xr[g] + h[n2].x * (1.0f / 1024.0f);
    }
}

extern "C" void kernel_launch(void* const* d_in, const int* in_sizes, int n_in,
                              void* d_out, int out_size, void* d_ws, size_t ws_size,
                              hipStream_t stream) {
    const float* x  = (const float*)d_in[0];
    const float* Wq = (const float*)d_in[1];
    const float* bq = (const float*)d_in[2];
    const float* Wk = (const float*)d_in[3];
    const float* bk = (const float*)d_in[4];
    const float* Wv = (const float*)d_in[5];
    const float* bv = (const float*)d_in[6];
    const float* Wr = (const float*)d_in[7];
    const float* br = (const float*)d_in[8];
    float* out = (float*)d_out;

    // ws: PKV (64MB interleaved __half2), Fs (32KB)
    __half2* PKV = (__half2*)d_ws;
    float2* Fs = (float2*)((char*)d_ws + (size_t)NROWS * D * 4);

    // d_out doubles as fp16 scratch until the final kernel rewrites all of it
    __half* Xh  = (__half*)d_out;
    __half* Whk = (__half*)d_out + (size_t)16 * 1024 * 1024;
    __half* Whv = Whk + (size_t)1024 * 1024;
    __half* Whq = Whv + (size_t)1024 * 1024;
    __half* Whr = Whq + (size_t)1024 * 1024;

    convert_all<<<16384 + 4 * 1024, 256, 0, stream>>>(
        x, Wk, Wv, Wq, Wr, Xh, Whk, Whv, Whq, Whr);

    hipMemsetAsync(Fs, 0, (size_t)BATCH * D * sizeof(float2), stream);

    gemm_mfma2<<<1024, 256, 0, stream>>>(Xh, Whk, bk, Whv, bv, PKV);
    bind_accum_kernel<<<NROWS / (2 * BROWS), 64, 0, stream>>>(
        (const unsigned int*)PKV, Fs);
    gemm_mfma2<<<1024, 256, 0, stream>>>(Xh, Whq, bq, Whr, br, PKV);
    retrieve_kernel<<<NROWS / RETR_ROWS, 128, 0, stream>>>(
        (const unsigned int*)PKV, Fs, x, out);
}

// Round 9
// 428.558 us; speedup vs baseline: 1.0185x; 1.0185x over previous
//
#include <hip/hip_runtime.h>
#include <hip/hip_fp16.h>

#define D 1024
#define LOG2D 10
#define S_LEN 4096
#define BATCH 4
#define NROWS (BATCH * S_LEN) /* 16384 */
#define PI_F 3.14159265358979323846f

typedef _Float16 f16x8 __attribute__((ext_vector_type(8)));
typedef float f32x4 __attribute__((ext_vector_type(4)));

__device__ __forceinline__ float2 cmul(float2 a, float2 b) {
    return make_float2(a.x * b.x - a.y * b.y, a.x * b.y + a.y * b.x);
}

__device__ __forceinline__ float fast_tanh(float v) {
    float e = __expf(2.0f * v);
    return 1.0f - 2.0f * __builtin_amdgcn_rcpf(e + 1.0f);
}

__device__ __forceinline__ void g2lds16(const void* g, void* l) {
    __builtin_amdgcn_global_load_lds(
        (const __attribute__((address_space(1))) unsigned int*)g,
        (__attribute__((address_space(3))) unsigned int*)l, 16, 0, 0);
}

// ---------------- fp32 -> fp16 conversion (x and the 4 weight matrices) ----
__global__ __launch_bounds__(256) void convert_all(
    const float* __restrict__ x,
    const float* __restrict__ w0, const float* __restrict__ w1,
    const float* __restrict__ w2, const float* __restrict__ w3,
    __half* __restrict__ xh,
    __half* __restrict__ h0, __half* __restrict__ h1,
    __half* __restrict__ h2, __half* __restrict__ h3)
{
    const int b = blockIdx.x;
    const float* s;
    __half* d;
    int li;
    if (b < 16384) { s = x; d = xh; li = b; }
    else {
        int t = b - 16384;
        int r = t >> 10;
        li = t & 1023;
        s = (r == 0) ? w0 : (r == 1) ? w1 : (r == 2) ? w2 : w3;
        d = (r == 0) ? h0 : (r == 1) ? h1 : (r == 2) ? h2 : h3;
    }
    const int idx = li * 256 + threadIdx.x;  // float4 index
    float4 v = ((const float4*)s)[idx];
    __half2 lo = __floats2half2_rn(v.x, v.y);
    __half2 hi = __floats2half2_rn(v.z, v.w);
    ((__half2*)d)[2 * idx + 0] = lo;
    ((__half2*)d)[2 * idx + 1] = hi;
}

// ------- Fused dual MFMA GEMM (round-1 proven structure, 89-91 us) --------
// O = {tanh(Xh*W0^T+b0), tanh(Xh*W1^T+b1)} stored INTERLEAVED as __half2.
// 128x128 tile, BK=64 (16 k-tiles, 64 MFMA per barrier pair), 256 thr.
// LDS [row][64] halves, 8 chunks of 16B per row, chunk q stored at slot
// q ^ (row&7) -> global_load_lds stays lane-contiguous, ds_read_b128 2-way max.
// XCD-swizzled block mapping for L2 locality.
__global__ __launch_bounds__(256, 2) void gemm_mfma2(
    const __half* __restrict__ Xh,
    const __half* __restrict__ W0, const float* __restrict__ b0,
    const __half* __restrict__ W1, const float* __restrict__ b1,
    __half2* __restrict__ KV)
{
    const int idx = blockIdx.x;
    const int xcd = idx & 7;
    const int j = idx >> 3;           // 0..127
    const int n0 = (j & 7) * 128;
    const int m0 = (xcd * 16 + (j >> 3)) * 128;

    __shared__ __align__(16) __half As[128 * 64];
    __shared__ __align__(16) __half B0s[128 * 64];
    __shared__ __align__(16) __half B1s[128 * 64];

    const int tid = threadIdx.x;
    const int wave = tid >> 6;
    const int lane = tid & 63;

    // staging: one g2lds = 64 lanes x 16B = 8 rows x 8 chunks.
    const int srow = lane >> 3;
    const int schunk = (lane & 7) ^ (lane >> 3);

    const __half* gA[4];
    const __half* gB0[4];
    const __half* gB1[4];
    int loff[4];
#pragma unroll
    for (int c = 0; c < 4; ++c) {
        const int rbase = wave * 32 + c * 8;         // multiple of 8
        gA[c]  = Xh + (size_t)(m0 + rbase + srow) * 1024 + schunk * 8;
        gB0[c] = W0 + (size_t)(n0 + rbase + srow) * 1024 + schunk * 8;
        gB1[c] = W1 + (size_t)(n0 + rbase + srow) * 1024 + schunk * 8;
        loff[c] = rbase * 64;                         // half units
    }

    const int wm = (wave & 1) * 64;
    const int wn = (wave >> 1) * 64;
    const int quad = lane >> 4;
    const int l15 = lane & 15;

    // frag read offsets: row R, k-slice kk (0/1): chunk c=(kk<<2)|quad at
    // slot c ^ (R&7); R&7 = l15&7 here (wm, i*16 are multiples of 8).
    int aoff[2][4], boff[2][4];
#pragma unroll
    for (int kk = 0; kk < 2; ++kk)
#pragma unroll
        for (int i = 0; i < 4; ++i) {
            const int Ra = wm + i * 16 + l15;
            aoff[kk][i] = Ra * 64 + ((((kk << 2) | quad)) ^ (l15 & 7)) * 8;
            const int Rb = wn + i * 16 + l15;
            boff[kk][i] = Rb * 64 + ((((kk << 2) | quad)) ^ (l15 & 7)) * 8;
        }

    f32x4 acc0[4][4], acc1[4][4];
#pragma unroll
    for (int i = 0; i < 4; ++i)
#pragma unroll
        for (int jj = 0; jj < 4; ++jj) {
            acc0[i][jj] = (f32x4){0.f, 0.f, 0.f, 0.f};
            acc1[i][jj] = (f32x4){0.f, 0.f, 0.f, 0.f};
        }

    for (int kt = 0; kt < 16; ++kt) {
        const int kh = kt * 64;
        __syncthreads();
#pragma unroll
        for (int c = 0; c < 4; ++c) {
            g2lds16(gA[c] + kh,  As  + loff[c]);
            g2lds16(gB0[c] + kh, B0s + loff[c]);
            g2lds16(gB1[c] + kh, B1s + loff[c]);
        }
        __syncthreads();

#pragma unroll
        for (int kk = 0; kk < 2; ++kk) {
            f16x8 af[4], bf0[4], bf1[4];
#pragma unroll
            for (int i = 0; i < 4; ++i) af[i] = *(const f16x8*)(As + aoff[kk][i]);
#pragma unroll
            for (int jj = 0; jj < 4; ++jj) {
                bf0[jj] = *(const f16x8*)(B0s + boff[kk][jj]);
                bf1[jj] = *(const f16x8*)(B1s + boff[kk][jj]);
            }
#pragma unroll
            for (int i = 0; i < 4; ++i)
#pragma unroll
                for (int jj = 0; jj < 4; ++jj) {
                    acc0[i][jj] = __builtin_amdgcn_mfma_f32_16x16x32_f16(af[i], bf0[jj], acc0[i][jj], 0, 0, 0);
                    acc1[i][jj] = __builtin_amdgcn_mfma_f32_16x16x32_f16(af[i], bf1[jj], acc1[i][jj], 0, 0, 0);
                }
        }
    }

    // epilogue: C/D frag mapping col=lane&15, row=quad*4+reg; interleaved pair
#pragma unroll
    for (int jj = 0; jj < 4; ++jj) {
        const int n = n0 + wn + jj * 16 + l15;
        const float bv0 = b0[n];
        const float bv1 = b1[n];
#pragma unroll
        for (int i = 0; i < 4; ++i) {
            const int mbase = m0 + wm + i * 16 + quad * 4;
#pragma unroll
            for (int r = 0; r < 4; ++r) {
                const __half h0 = __float2half(fast_tanh(acc0[i][jj][r] + bv0));
                const __half h1 = __float2half(fast_tanh(acc1[i][jj][r] + bv1));
                KV[(size_t)(mbase + r) * 1024 + n] = __halves2half2(h0, h1);
            }
        }
    }
}

// ================= register FFT-32 building blocks (proven) ================
__device__ constexpr int br5(int i) {
    return ((i & 1) << 4) | ((i & 2) << 2) | (i & 4) | ((i & 8) >> 2) | ((i & 16) >> 4);
}

// W32^k twiddles as compile-time constants (k static after unroll).
// INV=0: e^{-2pi i k/32}; INV=1: conjugate.
template<int INV>
__device__ __forceinline__ float2 w32c(int k) {
    constexpr float C[16] = {
        1.0f, 0.98078528f, 0.92387953f, 0.83146961f,
        0.70710678f, 0.55557023f, 0.38268343f, 0.19509032f,
        0.0f, -0.19509032f, -0.38268343f, -0.55557023f,
        -0.70710678f, -0.83146961f, -0.92387953f, -0.98078528f};
    constexpr float Sn[16] = {
        0.0f, 0.19509032f, 0.38268343f, 0.55557023f,
        0.70710678f, 0.83146961f, 0.92387953f, 0.98078528f,
        1.0f, 0.98078528f, 0.92387953f, 0.83146961f,
        0.70710678f, 0.55557023f, 0.38268343f, 0.19509032f};
    return make_float2(C[k], INV ? Sn[k] : -Sn[k]);
}

// In-register 32-point FFT. Input in registers bit-reversed, output natural.
template<int INV>
__device__ __forceinline__ void fft32(float2* z) {
#pragma unroll
    for (int s = 0; s < 5; ++s) {
#pragma unroll
        for (int j = 0; j < 16; ++j) {
            const int half = 1 << s;
            const int blk = j >> s;
            const int off = j & (half - 1);
            const int i0 = (blk << (s + 1)) + off;
            const int i1 = i0 + half;
            const float2 w = w32c<INV>(off << (4 - s));
            const float2 v = cmul(z[i1], w);
            z[i1] = make_float2(z[i0].x - v.x, z[i0].y - v.y);
            z[i0] = make_float2(z[i0].x + v.x, z[i0].y + v.y);
        }
    }
}

// ================= register-FFT bind kernel (forward only) =================
// For z = k + iv, P = Fk*Fv = W(j) + conj(W(-j)) with W = -i/4 Z^2
// (lane-local); symmetrization deferred to retrieve. Bind sums S = sum(W).
// REGISTER-PRESSURE FIX (r7 post-mortem): acc[32]+z[32] = 128+ VGPR live
// forced ~40 spilled regs/row (FETCH 104MB/WRITE 70MB vs 64/8 legit; the
// backend refuses >128 VGPR here regardless of waves_per_eu). The two
// half-wave groups produce contributions to the SAME 32 slots (different
// rows), so pair-exchange at the accumulate: px = P + shfl_xor(P,32) gives
// the row-pair sum; grp0 keeps k2<16, grp1 keeps k2>=16 -> acc[16]/lane.
// Peak live ~116 VGPR -> fits under 128, no spill, no extra LDS.
#define BROWS 4
__global__ __launch_bounds__(64) void bind_accum_kernel(
    const unsigned int* __restrict__ KV, float2* __restrict__ Fs)
{
    __shared__ float2 T[2][33 * 32];
    const int tid = threadIdx.x;
    const int grp = tid >> 5;
    const int t = tid & 31;
    const int row0 = blockIdx.x * (2 * BROWS) + grp * BROWS;
    const int b = row0 >> 12;   // 8-row chunks never straddle batches
    float2* Tr = T[grp];

    float sn_, cs_;
    __sincosf((PI_F / 512.0f) * (float)t, &sn_, &cs_);
    const float2 w1 = make_float2(cs_, -sn_);

    float2 acc[16];
#pragma unroll
    for (int i = 0; i < 16; ++i) acc[i] = make_float2(0.f, 0.f);
    const bool low = (grp == 0);

    for (int r = 0; r < BROWS; ++r) {
        const unsigned int* src = KV + ((size_t)(row0 + r) << 10);
        float2 z[32];
#pragma unroll
        for (int n1 = 0; n1 < 32; ++n1) {
            const unsigned int u = src[(n1 << 5) + t];
            const __half2 hv = *(const __half2*)&u;   // {K, V}
            z[br5(n1)] = make_float2(__half2float(hv.x), __half2float(hv.y));
        }
        fft32<0>(z);                 // A[k1] over n1
        {
            float2 tw = make_float2(1.0f, 0.0f);
#pragma unroll
            for (int k1 = 0; k1 < 32; ++k1) { z[k1] = cmul(z[k1], tw); tw = cmul(tw, w1); }
        }
        // transpose: write [k1][t], read [t][n2] (cross-lane, same wave ->
        // DS pipe in-order; sched_barrier pins compiler ordering)
#pragma unroll
        for (int k1 = 0; k1 < 32; ++k1) Tr[33 * k1 + t] = z[k1];
        __builtin_amdgcn_sched_barrier(0);
#pragma unroll
        for (int n2 = 0; n2 < 32; ++n2) z[br5(n2)] = Tr[33 * t + n2];
        fft32<0>(z);                 // Z[j], j = t + 32*k2
        __builtin_amdgcn_sched_barrier(0);  // next r's Tr writes stay after reads
        // W = -i/4 * Z^2 = (x*y/2, (y^2 - x^2)/4); pair-sum across the two
        // rows in this wave, keep only this group's half of the spectrum
#pragma unroll
        for (int k2 = 0; k2 < 32; ++k2) {
            const float zx = z[k2].x, zy = z[k2].y;
            const float wx = 0.5f * zx * zy;
            const float wy = 0.25f * (zy * zy - zx * zx);
            const float px = wx + __shfl_xor(wx, 32);
            const float py = wy + __shfl_xor(wy, 32);
            if ((k2 < 16) == low) {
                acc[k2 & 15].x += px;
                acc[k2 & 15].y += py;
            }
        }
    }

    // each lane owns 16 unique j slots: j = t + 32*(kb + m)
    const int kb = low ? 0 : 16;
    float2* FsB = Fs + ((size_t)b << 10);
#pragma unroll
    for (int m = 0; m < 16; ++m) {
        const int j = t + ((kb + m) << 5);
        atomicAdd(&FsB[j].x, acc[m].x);
        atomicAdd(&FsB[j].y, acc[m].y);
    }
}

// ===================== register-FFT retrieve kernel ========================
#define RETR_ROWS 4
__global__ __launch_bounds__(128) void retrieve_kernel(
    const unsigned int* __restrict__ QR,
    const float2* __restrict__ Fs, const float* __restrict__ x, float* __restrict__ out)
{
    // per-row transpose buffer, pad 33 (row stride 33 float2) -> conflict-free
    __shared__ __align__(16) float2 T[RETR_ROWS][33 * 32];
    const int tid = threadIdx.x;
    const int lr = tid >> 5;     // local row 0..3
    const int t  = tid & 31;     // lane within row = n2 / k1 / n1 role
    const int row = blockIdx.x * RETR_ROWS + lr;
    const int b = row >> 12;
    const size_t base = (size_t)row << 10;
    float2* Tr = T[lr];

    // ---- load z[n1] = Q + i*R at n = 32*n1 + t (interleaved u32) ---------
    float2 z[32];
    const unsigned int* src = QR + base;
#pragma unroll
    for (int n1 = 0; n1 < 32; ++n1) {
        const unsigned int u = src[(n1 << 5) + t];
        const __half2 hv = *(const __half2*)&u;   // {Q, R}
        z[br5(n1)] = make_float2(__half2float(hv.x), __half2float(hv.y));
    }
    fft32<0>(z);                     // A[k1] over n1 (natural order)

    // ---- middle twiddle W1024^{-t*k1}: sincos once + recurrence ----------
    float sn_, cs_;
    __sincosf((PI_F / 512.0f) * (float)t, &sn_, &cs_);
    {
        const float2 w1 = make_float2(cs_, -sn_);
        float2 tw = make_float2(1.0f, 0.0f);
#pragma unroll
        for (int k1 = 0; k1 < 32; ++k1) { z[k1] = cmul(z[k1], tw); tw = cmul(tw, w1); }
    }

    // ---- transpose #1: write [k1][t], read [t][n2] (bitrev into regs) ----
#pragma unroll
    for (int k1 = 0; k1 < 32; ++k1) Tr[33 * k1 + t] = z[k1];
    __syncthreads();
#pragma unroll
    for (int n2 = 0; n2 < 32; ++n2) z[br5(n2)] = Tr[33 * t + n2];
    fft32<0>(z);                     // z[k2] = Z[t + 32*k2]
    __syncthreads();                 // WAR: transpose reads done

    // ---- mirror round: Z -> LDS [k2][t]; read Z[1024-j] from mirror ------
#pragma unroll
    for (int k2 = 0; k2 < 32; ++k2) Tr[33 * k2 + t] = z[k2];
    __syncthreads();

    float2 h[32];
    const float2* FsB = Fs + ((size_t)b << 10);
    const int mc = (32 - t) & 31;
    const int me = (t == 0) ? 1 : 0;   // t=0 mirrors onto itself, shifted row
#pragma unroll
    for (int k2 = 0; k2 < 32; ++k2) {
        const int ma = (31 - k2 + me) & 31;
        float2 Zc = Tr[33 * ma + mc];
        Zc.y = -Zc.y;                  // conj(Z[1024-j])
        const float2 Zt = z[k2];       // Z[j], j = t + 32*k2
        const float2 Fq = make_float2(0.5f * (Zt.x + Zc.x), 0.5f * (Zt.y + Zc.y));
        const float2 Fr = make_float2(0.5f * (Zt.y - Zc.y), -0.5f * (Zt.x - Zc.x));
        const float2 g2 = make_float2(Fq.x - (Fr.x * Fr.x + Fr.y * Fr.y), -Fq.y);
        // Fs holds UNSYMMETRIZED S = sum(W); Ff = S[j] + conj(S[-j])
        const int jdx = (k2 << 5) + t;
        const float2 Sf = FsB[jdx];
        const float2 Sm = FsB[(1024 - jdx) & 1023];
        const float2 Ff = make_float2(Sf.x + Sm.x, Sf.y - Sm.y);
        h[br5(k2)] = cmul(Ff, g2);     // H[j], bitrev for inverse stage 1
    }

    // ---- inverse: same distribution (k = t mod 32) -> register-local -----
    fft32<1>(h);                     // over k1
    {
        const float2 w1c = make_float2(cs_, sn_);   // W1024^{+n1*t}
        float2 tw = make_float2(1.0f, 0.0f);
#pragma unroll
        for (int n1 = 0; n1 < 32; ++n1) { h[n1] = cmul(h[n1], tw); tw = cmul(tw, w1c); }
    }
    __syncthreads();                 // WAR: mirror reads done before overwrite
#pragma unroll
    for (int n1 = 0; n1 < 32; ++n1) Tr[33 * n1 + t] = h[n1];
    __syncthreads();
#pragma unroll
    for (int k2 = 0; k2 < 32; ++k2) h[br5(k2)] = Tr[33 * t + k2];
    fft32<1>(h);                     // h[n2] = y[t + 32*n2] (unscaled)

    // ---- out = x + real(y)/1024, coalesced (32 consecutive lanes) --------
    const float* xr = x + base;
    float* outr = out + base;
#pragma unroll
    for (int n2 = 0; n2 < 32; ++n2) {
        const int g = (n2 << 5) + t;
        outr[g] = xr[g] + h[n2].x * (1.0f / 1024.0f);
    }
}

extern "C" void kernel_launch(void* const* d_in, const int* in_sizes, int n_in,
                              void* d_out, int out_size, void* d_ws, size_t ws_size,
                              hipStream_t stream) {
    const float* x  = (const float*)d_in[0];
    const float* Wq = (const float*)d_in[1];
    const float* bq = (const float*)d_in[2];
    const float* Wk = (const float*)d_in[3];
    const float* bk = (const float*)d_in[4];
    const float* Wv = (const float*)d_in[5];
    const float* bv = (const float*)d_in[6];
    const float* Wr = (const float*)d_in[7];
    const float* br = (const float*)d_in[8];
    float* out = (float*)d_out;

    // ws: PKV (64MB interleaved __half2), Fs (32KB)
    __half2* PKV = (__half2*)d_ws;
    float2* Fs = (float2*)((char*)d_ws + (size_t)NROWS * D * 4);

    // d_out doubles as fp16 scratch until the final kernel rewrites all of it
    __half* Xh  = (__half*)d_out;
    __half* Whk = (__half*)d_out + (size_t)16 * 1024 * 1024;
    __half* Whv = Whk + (size_t)1024 * 1024;
    __half* Whq = Whv + (size_t)1024 * 1024;
    __half* Whr = Whq + (size_t)1024 * 1024;

    convert_all<<<16384 + 4 * 1024, 256, 0, stream>>>(
        x, Wk, Wv, Wq, Wr, Xh, Whk, Whv, Whq, Whr);

    hipMemsetAsync(Fs, 0, (size_t)BATCH * D * sizeof(float2), stream);

    gemm_mfma2<<<1024, 256, 0, stream>>>(Xh, Whk, bk, Whv, bv, PKV);
    bind_accum_kernel<<<NROWS / (2 * BROWS), 64, 0, stream>>>(
        (const unsigned int*)PKV, Fs);
    gemm_mfma2<<<1024, 256, 0, stream>>>(Xh, Whq, bq, Whr, br, PKV);
    retrieve_kernel<<<NROWS / RETR_ROWS, 128, 0, stream>>>(
        (const unsigned int*)PKV, Fs, x, out);
}